// Round 1
// baseline (174.779 us; speedup 1.0000x reference)
//
#include <hip/hip_runtime.h>

#define Bq 8
#define Sq 1024
#define Dq 512

typedef __attribute__((ext_vector_type(8))) short bf16x8;
typedef __attribute__((ext_vector_type(4))) float f32x4;

__device__ __forceinline__ unsigned short f2bf(float f) {
  unsigned int u = __float_as_uint(f);
  return (unsigned short)((u + 0x7fffu + ((u >> 16) & 1u)) >> 16);
}

__device__ __forceinline__ void load_lds16(const unsigned short* g, unsigned short* l) {
  __builtin_amdgcn_global_load_lds(
      (const __attribute__((address_space(1))) unsigned int*)g,
      (__attribute__((address_space(3))) unsigned int*)l, 16, 0, 0);
}

// ================= dispatch 1: prep_all (unchanged) =================
__global__ __launch_bounds__(256) void prep_all(
    const float* __restrict__ inp, const float* __restrict__ aspect,
    const float* __restrict__ w1, const float* __restrict__ w2,
    unsigned short* __restrict__ inpT, float* __restrict__ partial,
    unsigned short* __restrict__ asp_bf,
    unsigned short* __restrict__ w1b, unsigned short* __restrict__ w2b) {
  __shared__ unsigned short tile[32][33];
  __shared__ float csum[8][33];
  int idx = blockIdx.x;
  int tid = threadIdx.x;
  if (idx < 4096) {
    int b = idx & 7;
    int tt = (idx >> 3) & 31;
    int t0 = tt * 32, d0 = (idx >> 8) * 32;
    int tx = tid & 31, ty = tid >> 5;
    const float* src = inp + ((size_t)b * Sq + t0) * Dq + d0;
    float part = 0.f;
#pragma unroll
    for (int i = 0; i < 4; ++i) {
      float v = src[(size_t)(ty + i * 8) * Dq + tx];
      tile[ty + i * 8][tx] = f2bf(v);
      part += v;
    }
    csum[ty][tx] = part;
    __syncthreads();
    unsigned short* dst = inpT + (size_t)b * Dq * Sq;
#pragma unroll
    for (int i = 0; i < 4; ++i)
      dst[(size_t)(d0 + ty + i * 8) * Sq + t0 + tx] = tile[tx][ty + i * 8];
    if (ty == 0) {
      float s = 0.f;
#pragma unroll
      for (int i = 0; i < 8; ++i) s += csum[i][tx];
      partial[((size_t)b * 32 + tt) * Dq + d0 + tx] = s;
    }
  } else if (idx < 4608) {
    int blk = idx - 4096;
    const float* s = aspect + (size_t)blk * 8192 + tid * 4;
    unsigned short* d = asp_bf + (size_t)blk * 8192 + tid * 4;
#pragma unroll
    for (int j = 0; j < 8; ++j) {
      float4 v = *(const float4*)(s + j * 1024);
      ushort4 o; o.x = f2bf(v.x); o.y = f2bf(v.y); o.z = f2bf(v.z); o.w = f2bf(v.w);
      *(ushort4*)(d + j * 1024) = o;
    }
  } else {
    int blk = idx - 4608;
    const float* src = (blk < 256) ? w1 : w2;
    unsigned short* dst = (blk < 256) ? w1b : w2b;
    int i = ((blk & 255) * 256 + tid) * 4;
    float4 v = *(const float4*)(src + i);
    ushort4 o; o.x = f2bf(v.x); o.y = f2bf(v.y); o.z = f2bf(v.z); o.w = f2bf(v.w);
    *(ushort4*)(dst + i) = o;
  }
}

// ================= dispatch 2: gram_fac (unchanged) =================
__global__ __launch_bounds__(256, 5) void gram_fac(
    const unsigned short* __restrict__ inpT, const float* __restrict__ partial,
    const float* __restrict__ aspect, const float* __restrict__ lenv,
    unsigned short* __restrict__ Gm, float* __restrict__ fac) {
  __shared__ unsigned short sA[2][32 * 64];
  __shared__ unsigned short sB[2][64 * 64];
  int idx = blockIdx.x;
  int tid = threadIdx.x;
  int lane = tid & 63, wave = tid >> 6;

  if (idx >= 1024) {
    float* cs = (float*)sA;
    int fblk = idx - 1024;
    int b = fblk >> 6;
    int s0 = (fblk & 63) * 16;
#pragma unroll
    for (int h = 0; h < 2; ++h) {
      int d = h * 256 + tid;
      float s = 0.f;
      const float* p = partial + (size_t)b * 32 * Dq + d;
#pragma unroll
      for (int t = 0; t < 32; ++t) s += p[t * Dq];
      cs[d] = s;
    }
    __syncthreads();
    int g = lane >> 4, lr = lane & 15;
    int row = s0 + wave * 4 + g;
    const float* a = aspect + ((size_t)b * Sq + row) * Dq + lr * 32;
    float sum = 0.f;
#pragma unroll
    for (int j = 0; j < 8; ++j) {
      float4 v = *(const float4*)(a + j * 4);
      const float* c = cs + lr * 32 + j * 4;
      sum += v.x * c[0] + v.y * c[1] + v.z * c[2] + v.w * c[3];
    }
#pragma unroll
    for (int off = 1; off < 16; off <<= 1) sum += __shfl_xor(sum, off, 64);
    if (lr == 0) {
      float len = lenv[b];
      float scale = sqrtf(len);
      float f = 0.f;
      if (row < (int)len) f = 1.f / (scale * (sum / scale + 1e-4f));
      fac[b * Sq + row] = f;
    }
    return;
  }

  const int K = 1024;
  int b = idx & 7;
  int tile = idx >> 3;
  int bm = tile & 15, bn = tile >> 4;
  const unsigned short* Ab = inpT + (size_t)b * Dq * Sq + (size_t)bm * 32 * K;
  const unsigned short* Bb = inpT + (size_t)b * Dq * Sq + (size_t)bn * 64 * K;
  int lr = lane & 15, lq = lane >> 4;
  int x7 = lr & 7;
  int l3 = lane >> 3, l7 = lane & 7;

  const unsigned short* gA = Ab + (size_t)(wave * 8 + l3) * K + (l7 ^ l3) * 8;
  const unsigned short* gB = Bb + (size_t)(wave * 16 + l3) * K + (l7 ^ l3) * 8;
  int dbaseA = (wave * 64 + lane) * 8;
  int dbaseB0 = (wave * 128 + lane) * 8;
  int dbaseB1 = (wave * 128 + 64 + lane) * 8;

  f32x4 acc[2] = {};

  auto issue = [&](int buf, int k0) {
    load_lds16(gA + k0, &sA[buf][dbaseA]);
    load_lds16(gB + k0, &sB[buf][dbaseB0]);
    load_lds16(gB + (size_t)8 * K + k0, &sB[buf][dbaseB1]);
  };

  int wm = (wave & 1) * 16, wn = (wave >> 1) * 32;
  issue(0, 0);
#pragma unroll
  for (int it = 0; it < 16; ++it) {
    int cur = it & 1;
    __syncthreads();
    if (it + 1 < 16) issue(cur ^ 1, (it + 1) << 6);
#pragma unroll
    for (int c = 0; c < 2; ++c) {
      int g = c * 4 + lq;
      bf16x8 a0 = *(const bf16x8*)&sA[cur][((wm + lr) * 8 + (g ^ x7)) * 8];
      bf16x8 b0 = *(const bf16x8*)&sB[cur][((wn + lr) * 8 + (g ^ x7)) * 8];
      bf16x8 b1 = *(const bf16x8*)&sB[cur][((wn + 16 + lr) * 8 + (g ^ x7)) * 8];
      acc[0] = __builtin_amdgcn_mfma_f32_16x16x32_bf16(a0, b0, acc[0], 0, 0, 0);
      acc[1] = __builtin_amdgcn_mfma_f32_16x16x32_bf16(a0, b1, acc[1], 0, 0, 0);
    }
  }

  unsigned short* Ob = Gm + (size_t)b * 512 * 512;
#pragma unroll
  for (int ni = 0; ni < 2; ++ni)
#pragma unroll
    for (int i = 0; i < 4; ++i) {
      int r = bm * 32 + wm + lq * 4 + i;
      int cc = bn * 64 + wn + ni * 16 + lr;
      Ob[(size_t)r * 512 + cc] = f2bf(acc[ni][i]);
    }
}

// ================= dispatch 3: mega — barrier-free wave-private-B GEMMs =====
// 256 blocks x 512 thr. Each block: 32 rows. 8 waves, each wave owns 64 cols
// exclusively -> B fragments read directly from L2 (no LDS staging, no in-loop
// __syncthreads). Each B frag reused for both 16-row groups in-register.
// blockIdx swizzled so batch b -> XCD b (matches gram_fac's idx&7 pinning; G[b]
// is already hot in that XCD's L2).
#define LP 520  // padded lds row stride (shorts); 1040B = 65x16B, conflict-free b128

__global__ __launch_bounds__(512, 2) void mega_ffn(
    const unsigned short* __restrict__ aspb, const unsigned short* __restrict__ G,
    const unsigned short* __restrict__ w1b, const unsigned short* __restrict__ w2b,
    const float* __restrict__ b1, const float* __restrict__ b2,
    const float* __restrict__ inp, const float* __restrict__ aspect,
    const float* __restrict__ fac, const float* __restrict__ lenv,
    float* __restrict__ out) {
  __shared__ unsigned short ldsA[32 * LP];  // 33280 B: ffn_inp / o1 row tile
  __shared__ float ssqW[256];               // 8 waves x 32 rows
  int tid = threadIdx.x;
  int lane = tid & 63, wave = tid >> 6;
  int lr = lane & 15, lq = lane >> 4;
  int bid = ((blockIdx.x & 7) << 5) | (blockIdx.x >> 3);  // batch -> XCD pin
  int r0 = bid * 32;
  int b = r0 >> 10;
  int c0 = wave * 64;

  f32x4 acc[2][4];
  float ffnv[2][4][4];

  const unsigned short* Gb = G + (size_t)b * 512 * 512;

  // --- barrier-free GEMM over K=512: acc[mg][t] += A(rows)xB(cols c0+64) ---
  auto gemmLoop = [&](const unsigned short* Bp, auto loadA) {
    auto loadB = [&](int kc, bf16x8* dst) {
#pragma unroll
      for (int t = 0; t < 4; ++t)
        dst[t] = *(const bf16x8*)(Bp + (size_t)(c0 + t * 16 + lr) * 512 + kc * 32 + lq * 8);
    };
    bf16x8 aC[2], bC[4], aN[2], bN[4];
#pragma unroll
    for (int mg = 0; mg < 2; ++mg)
#pragma unroll
      for (int t = 0; t < 4; ++t) acc[mg][t] = (f32x4){0.f, 0.f, 0.f, 0.f};
    loadA(0, aC);
    loadB(0, bC);
#pragma unroll
    for (int kc = 0; kc < 16; ++kc) {
      if (kc < 15) {  // depth-1 register prefetch; loads fly under the 8 MFMAs
        loadA(kc + 1, aN);
        loadB(kc + 1, bN);
      }
#pragma unroll
      for (int t = 0; t < 4; ++t) {
        acc[0][t] = __builtin_amdgcn_mfma_f32_16x16x32_bf16(aC[0], bC[t], acc[0][t], 0, 0, 0);
        acc[1][t] = __builtin_amdgcn_mfma_f32_16x16x32_bf16(aC[1], bC[t], acc[1][t], 0, 0, 0);
      }
#pragma unroll
      for (int m = 0; m < 2; ++m) aC[m] = aN[m];
#pragma unroll
      for (int t = 0; t < 4; ++t) bC[t] = bN[t];
    }
  };

  auto loadA_g = [&](int kc, bf16x8* dst) {  // phase 0: A = aspect rows (global bf16)
    dst[0] = *(const bf16x8*)(aspb + (size_t)(r0 + lr) * 512 + kc * 32 + lq * 8);
    dst[1] = *(const bf16x8*)(aspb + (size_t)(r0 + 16 + lr) * 512 + kc * 32 + lq * 8);
  };
  auto loadA_l = [&](int kc, bf16x8* dst) {  // phase 1/2: A = ldsA rows
    dst[0] = *(const bf16x8*)&ldsA[(size_t)lr * LP + kc * 32 + lq * 8];
    dst[1] = *(const bf16x8*)&ldsA[(size_t)(16 + lr) * LP + kc * 32 + lq * 8];
  };

  // ================= phase 0: weighted = aspect @ G, + residual =================
  gemmLoop(Gb, loadA_g);
  int len = (int)lenv[b];
  float facv[2][4];
#pragma unroll
  for (int mg = 0; mg < 2; ++mg)
#pragma unroll
    for (int i = 0; i < 4; ++i) facv[mg][i] = fac[r0 + mg * 16 + lq * 4 + i];
#pragma unroll
  for (int mg = 0; mg < 2; ++mg)
#pragma unroll
    for (int t = 0; t < 4; ++t)
#pragma unroll
      for (int i = 0; i < 4; ++i) {
        int rr = mg * 16 + lq * 4 + i;
        int r = r0 + rr;
        size_t idx = (size_t)r * 512 + c0 + t * 16 + lr;
        float add = ((r & 1023) < len) ? (inp[idx] + aspect[idx]) : 0.f;
        float v = acc[mg][t][i] * facv[mg][i] + add;
        ffnv[mg][t][i] = v;
        ldsA[rr * LP + c0 + t * 16 + lr] = f2bf(v);
      }
  __syncthreads();

  // ================= phase 1: o1 = relu(ffn_inp @ w1^T + b1) =================
  gemmLoop(w1b, loadA_l);
  float biasv[4];
#pragma unroll
  for (int t = 0; t < 4; ++t) biasv[t] = b1[c0 + t * 16 + lr];
  __syncthreads();  // all ldsA reads of phase 1 done before overwrite
#pragma unroll
  for (int mg = 0; mg < 2; ++mg)
#pragma unroll
    for (int t = 0; t < 4; ++t)
#pragma unroll
      for (int i = 0; i < 4; ++i) {
        int rr = mg * 16 + lq * 4 + i;
        ldsA[rr * LP + c0 + t * 16 + lr] = f2bf(fmaxf(acc[mg][t][i] + biasv[t], 0.f));
      }
  __syncthreads();

  // ================= phase 2: o2 + combine + L2-norm =================
  gemmLoop(w2b, loadA_l);
#pragma unroll
  for (int t = 0; t < 4; ++t) biasv[t] = b2[c0 + t * 16 + lr];
  float ssq[2][4] = {{0.f, 0.f, 0.f, 0.f}, {0.f, 0.f, 0.f, 0.f}};
#pragma unroll
  for (int mg = 0; mg < 2; ++mg)
#pragma unroll
    for (int t = 0; t < 4; ++t)
#pragma unroll
      for (int i = 0; i < 4; ++i) {
        float v = 2.f * ffnv[mg][t][i] + fmaxf(acc[mg][t][i] + biasv[t], 0.f);
        ffnv[mg][t][i] = v;
        ssq[mg][i] += v * v;
      }
#pragma unroll
  for (int off = 1; off < 16; off <<= 1)
#pragma unroll
    for (int mg = 0; mg < 2; ++mg)
#pragma unroll
      for (int i = 0; i < 4; ++i) ssq[mg][i] += __shfl_xor(ssq[mg][i], off, 64);
  if (lr == 0)
#pragma unroll
    for (int mg = 0; mg < 2; ++mg)
#pragma unroll
      for (int i = 0; i < 4; ++i) ssqW[wave * 32 + mg * 16 + lq * 4 + i] = ssq[mg][i];
  __syncthreads();
  float rn[2][4];
#pragma unroll
  for (int mg = 0; mg < 2; ++mg)
#pragma unroll
    for (int i = 0; i < 4; ++i) {
      float s = 0.f;
#pragma unroll
      for (int w = 0; w < 8; ++w) s += ssqW[w * 32 + mg * 16 + lq * 4 + i];
      rn[mg][i] = 1.f / sqrtf(s);
    }
#pragma unroll
  for (int mg = 0; mg < 2; ++mg)
#pragma unroll
    for (int t = 0; t < 4; ++t)
#pragma unroll
      for (int i = 0; i < 4; ++i) {
        int r = r0 + mg * 16 + lq * 4 + i;
        out[(size_t)r * 512 + c0 + t * 16 + lr] = ffnv[mg][t][i] * rn[mg][i];
      }
}

extern "C" void kernel_launch(void* const* d_in, const int* in_sizes, int n_in,
                              void* d_out, int out_size, void* d_ws, size_t ws_size,
                              hipStream_t stream) {
  const float* inp = (const float*)d_in[0];
  const float* inp_len = (const float*)d_in[1];
  const float* aspect = (const float*)d_in[2];
  const float* w1 = (const float*)d_in[3];
  const float* b1 = (const float*)d_in[4];
  const float* w2 = (const float*)d_in[5];
  const float* b2 = (const float*)d_in[6];
  float* out = (float*)d_out;

  char* W = (char*)d_ws;
  const size_t MB = 1ull << 20;
  unsigned short* asp_bf = (unsigned short*)(W + 0);        // 8 MB
  unsigned short* inpT   = (unsigned short*)(W + 8 * MB);   // 8 MB
  unsigned short* Gm     = (unsigned short*)(W + 16 * MB);  // 4 MB
  unsigned short* w1bf   = (unsigned short*)(W + 20 * MB);  // 512 KB
  unsigned short* w2bf   = (unsigned short*)(W + 20 * MB + 512 * 1024);
  float*          partial= (float*)(W + 21 * MB);           // 512 KB
  float*          fac    = (float*)(W + 22 * MB);           // 32 KB

  prep_all<<<5120, 256, 0, stream>>>(inp, aspect, w1, w2,
                                     inpT, partial, asp_bf, w1bf, w2bf);

  gram_fac<<<1536, 256, 0, stream>>>(inpT, partial, aspect, inp_len, Gm, fac);

  mega_ffn<<<256, 512, 0, stream>>>(
      asp_bf, Gm, w1bf, w2bf, b1, b2, inp, aspect, fac, inp_len, out);
}

// Round 2
// 150.541 us; speedup vs baseline: 1.1610x; 1.1610x over previous
//
#include <hip/hip_runtime.h>

#define Bq 8
#define Sq 1024
#define Dq 512

typedef __attribute__((ext_vector_type(8))) short bf16x8;
typedef __attribute__((ext_vector_type(4))) float f32x4;

__device__ __forceinline__ unsigned short f2bf(float f) {
  unsigned int u = __float_as_uint(f);
  return (unsigned short)((u + 0x7fffu + ((u >> 16) & 1u)) >> 16);
}

__device__ __forceinline__ void load_lds16(const unsigned short* g, unsigned short* l) {
  __builtin_amdgcn_global_load_lds(
      (const __attribute__((address_space(1))) unsigned int*)g,
      (__attribute__((address_space(3))) unsigned int*)l, 16, 0, 0);
}

// ================= dispatch 1: prep_all (unchanged) =================
__global__ __launch_bounds__(256) void prep_all(
    const float* __restrict__ inp, const float* __restrict__ aspect,
    const float* __restrict__ w1, const float* __restrict__ w2,
    unsigned short* __restrict__ inpT, float* __restrict__ partial,
    unsigned short* __restrict__ asp_bf,
    unsigned short* __restrict__ w1b, unsigned short* __restrict__ w2b) {
  __shared__ unsigned short tile[32][33];
  __shared__ float csum[8][33];
  int idx = blockIdx.x;
  int tid = threadIdx.x;
  if (idx < 4096) {
    int b = idx & 7;
    int tt = (idx >> 3) & 31;
    int t0 = tt * 32, d0 = (idx >> 8) * 32;
    int tx = tid & 31, ty = tid >> 5;
    const float* src = inp + ((size_t)b * Sq + t0) * Dq + d0;
    float part = 0.f;
#pragma unroll
    for (int i = 0; i < 4; ++i) {
      float v = src[(size_t)(ty + i * 8) * Dq + tx];
      tile[ty + i * 8][tx] = f2bf(v);
      part += v;
    }
    csum[ty][tx] = part;
    __syncthreads();
    unsigned short* dst = inpT + (size_t)b * Dq * Sq;
#pragma unroll
    for (int i = 0; i < 4; ++i)
      dst[(size_t)(d0 + ty + i * 8) * Sq + t0 + tx] = tile[tx][ty + i * 8];
    if (ty == 0) {
      float s = 0.f;
#pragma unroll
      for (int i = 0; i < 8; ++i) s += csum[i][tx];
      partial[((size_t)b * 32 + tt) * Dq + d0 + tx] = s;
    }
  } else if (idx < 4608) {
    int blk = idx - 4096;
    const float* s = aspect + (size_t)blk * 8192 + tid * 4;
    unsigned short* d = asp_bf + (size_t)blk * 8192 + tid * 4;
#pragma unroll
    for (int j = 0; j < 8; ++j) {
      float4 v = *(const float4*)(s + j * 1024);
      ushort4 o; o.x = f2bf(v.x); o.y = f2bf(v.y); o.z = f2bf(v.z); o.w = f2bf(v.w);
      *(ushort4*)(d + j * 1024) = o;
    }
  } else {
    int blk = idx - 4608;
    const float* src = (blk < 256) ? w1 : w2;
    unsigned short* dst = (blk < 256) ? w1b : w2b;
    int i = ((blk & 255) * 256 + tid) * 4;
    float4 v = *(const float4*)(src + i);
    ushort4 o; o.x = f2bf(v.x); o.y = f2bf(v.y); o.z = f2bf(v.z); o.w = f2bf(v.w);
    *(ushort4*)(dst + i) = o;
  }
}

// ================= dispatch 2: gram_fac (T4: counted vmcnt + 2-barrier) ======
__global__ __launch_bounds__(256, 5) void gram_fac(
    const unsigned short* __restrict__ inpT, const float* __restrict__ partial,
    const float* __restrict__ aspect, const float* __restrict__ lenv,
    unsigned short* __restrict__ Gm, float* __restrict__ fac) {
  __shared__ unsigned short sA[2][32 * 64];
  __shared__ unsigned short sB[2][64 * 64];
  int idx = blockIdx.x;
  int tid = threadIdx.x;
  int lane = tid & 63, wave = tid >> 6;

  if (idx >= 1024) {
    float* cs = (float*)sA;
    int fblk = idx - 1024;
    int b = fblk >> 6;
    int s0 = (fblk & 63) * 16;
#pragma unroll
    for (int h = 0; h < 2; ++h) {
      int d = h * 256 + tid;
      float s = 0.f;
      const float* p = partial + (size_t)b * 32 * Dq + d;
#pragma unroll
      for (int t = 0; t < 32; ++t) s += p[t * Dq];
      cs[d] = s;
    }
    __syncthreads();
    int g = lane >> 4, lr = lane & 15;
    int row = s0 + wave * 4 + g;
    const float* a = aspect + ((size_t)b * Sq + row) * Dq + lr * 32;
    float sum = 0.f;
#pragma unroll
    for (int j = 0; j < 8; ++j) {
      float4 v = *(const float4*)(a + j * 4);
      const float* c = cs + lr * 32 + j * 4;
      sum += v.x * c[0] + v.y * c[1] + v.z * c[2] + v.w * c[3];
    }
#pragma unroll
    for (int off = 1; off < 16; off <<= 1) sum += __shfl_xor(sum, off, 64);
    if (lr == 0) {
      float len = lenv[b];
      float scale = sqrtf(len);
      float f = 0.f;
      if (row < (int)len) f = 1.f / (scale * (sum / scale + 1e-4f));
      fac[b * Sq + row] = f;
    }
    return;
  }

  const int K = 1024;
  int b = idx & 7;
  int tile = idx >> 3;
  int bm = tile & 15, bn = tile >> 4;
  const unsigned short* Ab = inpT + (size_t)b * Dq * Sq + (size_t)bm * 32 * K;
  const unsigned short* Bb = inpT + (size_t)b * Dq * Sq + (size_t)bn * 64 * K;
  int lr = lane & 15, lq = lane >> 4;
  int x7 = lr & 7;
  int l3 = lane >> 3, l7 = lane & 7;

  const unsigned short* gA = Ab + (size_t)(wave * 8 + l3) * K + (l7 ^ l3) * 8;
  const unsigned short* gB = Bb + (size_t)(wave * 16 + l3) * K + (l7 ^ l3) * 8;
  int dbaseA = (wave * 64 + lane) * 8;
  int dbaseB0 = (wave * 128 + lane) * 8;
  int dbaseB1 = (wave * 128 + 64 + lane) * 8;

  f32x4 acc[2] = {};

  auto issue = [&](int buf, int k0) {
    load_lds16(gA + k0, &sA[buf][dbaseA]);
    load_lds16(gB + k0, &sB[buf][dbaseB0]);
    load_lds16(gB + (size_t)8 * K + k0, &sB[buf][dbaseB1]);
  };

  int wm = (wave & 1) * 16, wn = (wave >> 1) * 32;
  issue(0, 0);
#pragma unroll
  for (int it = 0; it < 16; ++it) {
    int cur = it & 1;
    // issue next tile into the buffer everyone finished reading (barrier B of
    // it-1 guarantees that), then wait only for THIS tile's 3 loads (the 3
    // newest stay in flight across the barrier).
    if (it + 1 < 16) {
      issue(cur ^ 1, (it + 1) << 6);
      asm volatile("s_waitcnt vmcnt(3)" ::: "memory");
    } else {
      asm volatile("s_waitcnt vmcnt(0)" ::: "memory");
    }
    __builtin_amdgcn_s_barrier();  // barrier A: tile `it` staged for all waves
#pragma unroll
    for (int c = 0; c < 2; ++c) {
      int g = c * 4 + lq;
      bf16x8 a0 = *(const bf16x8*)&sA[cur][((wm + lr) * 8 + (g ^ x7)) * 8];
      bf16x8 b0 = *(const bf16x8*)&sB[cur][((wn + lr) * 8 + (g ^ x7)) * 8];
      bf16x8 b1 = *(const bf16x8*)&sB[cur][((wn + 16 + lr) * 8 + (g ^ x7)) * 8];
      acc[0] = __builtin_amdgcn_mfma_f32_16x16x32_bf16(a0, b0, acc[0], 0, 0, 0);
      acc[1] = __builtin_amdgcn_mfma_f32_16x16x32_bf16(a0, b1, acc[1], 0, 0, 0);
    }
    asm volatile("s_waitcnt lgkmcnt(0)" ::: "memory");  // my reads drained
    __builtin_amdgcn_sched_barrier(0);                  // rule #18: pin them
    __builtin_amdgcn_s_barrier();  // barrier B: buf[cur] free to overwrite
  }

  unsigned short* Ob = Gm + (size_t)b * 512 * 512;
#pragma unroll
  for (int ni = 0; ni < 2; ++ni)
#pragma unroll
    for (int i = 0; i < 4; ++i) {
      int r = bm * 32 + wm + lq * 4 + i;
      int cc = bn * 64 + wn + ni * 16 + lr;
      Ob[(size_t)r * 512 + cc] = f2bf(acc[ni][i]);
    }
}

// ================= dispatch 3: mega (round-0 structure + T4 counted vmcnt) ===
#define LP 520
#define MEGA_SMEM (32 * LP * 2 + 2 * 32768 + 512)

__global__ __launch_bounds__(512, 2) void mega_ffn(
    const unsigned short* __restrict__ aspb, const unsigned short* __restrict__ G,
    const unsigned short* __restrict__ w1b, const unsigned short* __restrict__ w2b,
    const float* __restrict__ b1, const float* __restrict__ b2,
    const float* __restrict__ inp, const float* __restrict__ aspect,
    const float* __restrict__ fac, const float* __restrict__ lenv,
    float* __restrict__ out) {
  extern __shared__ char smem[];
  unsigned short* ldsA = (unsigned short*)smem;
  unsigned short* wbuf = (unsigned short*)(smem + 32 * LP * 2);
  float* ssqW = (float*)(smem + 32 * LP * 2 + 2 * 32768);
  int tid = threadIdx.x;
  int lane = tid & 63, wave = tid >> 6;
  int mg = wave >> 2, ng = wave & 3;
  int lr = lane & 15, lq = lane >> 4;
  int bid = ((blockIdx.x & 7) << 5) | (blockIdx.x >> 3);  // batch -> XCD pin
  int r0 = bid * 32;
  int b = r0 >> 10;
  int c0 = ng * 128;
  int arow = r0 + mg * 16 + lr;

  bf16x8 af[16];
  f32x4 acc[8];
  f32x4 ffnv[8];

  auto stage = [&](int buf, int kc, const unsigned short* Bsrc) {
#pragma unroll
    for (int i = 0; i < 4; ++i) {
      int n = i * 128 + wave * 16 + (lane >> 2);
      load_lds16(Bsrc + (size_t)n * 512 + kc * 32 + (lane & 3) * 8,
                 wbuf + buf * 16384 + (size_t)(i * 512 + wave * 64 + lane) * 8);
    }
  };

  // K-loop: A in registers (af), B double-buffer staged via global_load_lds.
  // Counted vmcnt: the 4 just-issued loads for kc+1 stay in flight across the
  // barrier; only kc's 4 must have landed. Two raw barriers per step make the
  // double-buffer race-free (writes to a buffer are issued only after the
  // barrier that all its readers passed with lgkmcnt(0) drained).
  auto gemmPhase = [&](const unsigned short* Bsrc) {
#pragma unroll
    for (int t = 0; t < 8; ++t) acc[t] = (f32x4){0.f, 0.f, 0.f, 0.f};
    stage(0, 0, Bsrc);
#pragma unroll
    for (int kc = 0; kc < 16; ++kc) {
      int cur = kc & 1;
      if (kc < 15) {
        stage(cur ^ 1, kc + 1, Bsrc);
        asm volatile("s_waitcnt vmcnt(4)" ::: "memory");
      } else {
        asm volatile("s_waitcnt vmcnt(0)" ::: "memory");
      }
      __builtin_amdgcn_s_barrier();  // barrier A: tile kc staged
      bf16x8 bfr[8];
#pragma unroll
      for (int t = 0; t < 8; ++t)
        bfr[t] = *(const bf16x8*)&wbuf[cur * 16384 + (size_t)((c0 + t * 16 + lr) * 4 + lq) * 8];
#pragma unroll
      for (int t = 0; t < 8; ++t)
        acc[t] = __builtin_amdgcn_mfma_f32_16x16x32_bf16(af[kc], bfr[t], acc[t], 0, 0, 0);
      asm volatile("s_waitcnt lgkmcnt(0)" ::: "memory");
      __builtin_amdgcn_sched_barrier(0);
      __builtin_amdgcn_s_barrier();  // barrier B: buf[cur] free
    }
  };

  // phase 0
#pragma unroll
  for (int j = 0; j < 16; ++j)
    af[j] = *(const bf16x8*)(aspb + (size_t)arow * 512 + j * 32 + lq * 8);
  gemmPhase(G + (size_t)b * 512 * 512);
  int len = (int)lenv[b];
  float facv[4];
#pragma unroll
  for (int i = 0; i < 4; ++i) facv[i] = fac[r0 + mg * 16 + lq * 4 + i];
#pragma unroll
  for (int t = 0; t < 8; ++t) {
#pragma unroll
    for (int i = 0; i < 4; ++i) {
      int r = r0 + mg * 16 + lq * 4 + i;
      size_t idx = (size_t)r * 512 + c0 + t * 16 + lr;
      float add = ((r & 1023) < len) ? (inp[idx] + aspect[idx]) : 0.f;
      float v = acc[t][i] * facv[i] + add;
      ffnv[t][i] = v;
      ldsA[(mg * 16 + lq * 4 + i) * LP + c0 + t * 16 + lr] = f2bf(v);
    }
  }
  __syncthreads();

  // phase 1
#pragma unroll
  for (int j = 0; j < 16; ++j)
    af[j] = *(const bf16x8*)&ldsA[(mg * 16 + lr) * LP + j * 32 + lq * 8];
  __syncthreads();
  gemmPhase(w1b);
  float biasv[8];
#pragma unroll
  for (int t = 0; t < 8; ++t) biasv[t] = b1[c0 + t * 16 + lr];
#pragma unroll
  for (int t = 0; t < 8; ++t)
#pragma unroll
    for (int i = 0; i < 4; ++i)
      ldsA[(mg * 16 + lq * 4 + i) * LP + c0 + t * 16 + lr] =
          f2bf(fmaxf(acc[t][i] + biasv[t], 0.f));
  __syncthreads();

  // phase 2 + norm
#pragma unroll
  for (int j = 0; j < 16; ++j)
    af[j] = *(const bf16x8*)&ldsA[(mg * 16 + lr) * LP + j * 32 + lq * 8];
  __syncthreads();
  gemmPhase(w2b);
#pragma unroll
  for (int t = 0; t < 8; ++t) biasv[t] = b2[c0 + t * 16 + lr];
  float ssq[4] = {0.f, 0.f, 0.f, 0.f};
#pragma unroll
  for (int t = 0; t < 8; ++t)
#pragma unroll
    for (int i = 0; i < 4; ++i) {
      float v = 2.f * ffnv[t][i] + fmaxf(acc[t][i] + biasv[t], 0.f);
      ffnv[t][i] = v;
      ssq[i] += v * v;
    }
#pragma unroll
  for (int off = 1; off < 16; off <<= 1)
#pragma unroll
    for (int i = 0; i < 4; ++i) ssq[i] += __shfl_xor(ssq[i], off, 64);
  if (lr == 0)
#pragma unroll
    for (int i = 0; i < 4; ++i) ssqW[(mg * 4 + ng) * 16 + lq * 4 + i] = ssq[i];
  __syncthreads();
  float rn[4];
#pragma unroll
  for (int i = 0; i < 4; ++i) {
    float s = ssqW[(mg * 4 + 0) * 16 + lq * 4 + i] + ssqW[(mg * 4 + 1) * 16 + lq * 4 + i] +
              ssqW[(mg * 4 + 2) * 16 + lq * 4 + i] + ssqW[(mg * 4 + 3) * 16 + lq * 4 + i];
    rn[i] = 1.f / sqrtf(s);
  }
#pragma unroll
  for (int t = 0; t < 8; ++t)
#pragma unroll
    for (int i = 0; i < 4; ++i) {
      int r = r0 + mg * 16 + lq * 4 + i;
      out[(size_t)r * 512 + c0 + t * 16 + lr] = ffnv[t][i] * rn[i];
    }
}

extern "C" void kernel_launch(void* const* d_in, const int* in_sizes, int n_in,
                              void* d_out, int out_size, void* d_ws, size_t ws_size,
                              hipStream_t stream) {
  const float* inp = (const float*)d_in[0];
  const float* inp_len = (const float*)d_in[1];
  const float* aspect = (const float*)d_in[2];
  const float* w1 = (const float*)d_in[3];
  const float* b1 = (const float*)d_in[4];
  const float* w2 = (const float*)d_in[5];
  const float* b2 = (const float*)d_in[6];
  float* out = (float*)d_out;

  char* W = (char*)d_ws;
  const size_t MB = 1ull << 20;
  unsigned short* asp_bf = (unsigned short*)(W + 0);        // 8 MB
  unsigned short* inpT   = (unsigned short*)(W + 8 * MB);   // 8 MB
  unsigned short* Gm     = (unsigned short*)(W + 16 * MB);  // 4 MB
  unsigned short* w1bf   = (unsigned short*)(W + 20 * MB);  // 512 KB
  unsigned short* w2bf   = (unsigned short*)(W + 20 * MB + 512 * 1024);
  float*          partial= (float*)(W + 21 * MB);           // 512 KB
  float*          fac    = (float*)(W + 22 * MB);           // 32 KB

  prep_all<<<5120, 256, 0, stream>>>(inp, aspect, w1, w2,
                                     inpT, partial, asp_bf, w1bf, w2bf);

  gram_fac<<<1536, 256, 0, stream>>>(inpT, partial, aspect, inp_len, Gm, fac);

  hipFuncSetAttribute((const void*)mega_ffn,
                      hipFuncAttributeMaxDynamicSharedMemorySize, MEGA_SMEM);
  mega_ffn<<<256, 512, MEGA_SMEM, stream>>>(
      asp_bf, Gm, w1bf, w2bf, b1, b2, inp, aspect, fac, inp_len, out);
}

// Round 3
// 144.516 us; speedup vs baseline: 1.2094x; 1.0417x over previous
//
#include <hip/hip_runtime.h>

#define Bq 8
#define Sq 1024
#define Dq 512

typedef __attribute__((ext_vector_type(8))) short bf16x8;
typedef __attribute__((ext_vector_type(4))) float f32x4;

__device__ __forceinline__ unsigned short f2bf(float f) {
  unsigned int u = __float_as_uint(f);
  return (unsigned short)((u + 0x7fffu + ((u >> 16) & 1u)) >> 16);
}

__device__ __forceinline__ void load_lds16(const unsigned short* g, unsigned short* l) {
  __builtin_amdgcn_global_load_lds(
      (const __attribute__((address_space(1))) unsigned int*)g,
      (__attribute__((address_space(3))) unsigned int*)l, 16, 0, 0);
}

// Permuted B layout ("k-chunk-major"): element B[n][k] lives at
//   kc*16384 + (n*4 + ((k&31)>>3))*8 + (k&7),   kc = k>>5
// i.e. 16 chunks of 32KB, each chunk exactly the LDS staging image.

// ================= dispatch 1: prep_all =================
// f2 (w cast) now writes the permuted layout.
__global__ __launch_bounds__(256) void prep_all(
    const float* __restrict__ inp, const float* __restrict__ aspect,
    const float* __restrict__ w1, const float* __restrict__ w2,
    unsigned short* __restrict__ inpT, float* __restrict__ partial,
    unsigned short* __restrict__ asp_bf,
    unsigned short* __restrict__ w1b, unsigned short* __restrict__ w2b) {
  __shared__ unsigned short tile[32][33];
  __shared__ float csum[8][33];
  int idx = blockIdx.x;
  int tid = threadIdx.x;
  if (idx < 4096) {
    int b = idx & 7;
    int tt = (idx >> 3) & 31;
    int t0 = tt * 32, d0 = (idx >> 8) * 32;
    int tx = tid & 31, ty = tid >> 5;
    const float* src = inp + ((size_t)b * Sq + t0) * Dq + d0;
    float part = 0.f;
#pragma unroll
    for (int i = 0; i < 4; ++i) {
      float v = src[(size_t)(ty + i * 8) * Dq + tx];
      tile[ty + i * 8][tx] = f2bf(v);
      part += v;
    }
    csum[ty][tx] = part;
    __syncthreads();
    unsigned short* dst = inpT + (size_t)b * Dq * Sq;
#pragma unroll
    for (int i = 0; i < 4; ++i)
      dst[(size_t)(d0 + ty + i * 8) * Sq + t0 + tx] = tile[tx][ty + i * 8];
    if (ty == 0) {
      float s = 0.f;
#pragma unroll
      for (int i = 0; i < 8; ++i) s += csum[i][tx];
      partial[((size_t)b * 32 + tt) * Dq + d0 + tx] = s;
    }
  } else if (idx < 4608) {
    int blk = idx - 4096;
    const float* s = aspect + (size_t)blk * 8192 + tid * 4;
    unsigned short* d = asp_bf + (size_t)blk * 8192 + tid * 4;
#pragma unroll
    for (int j = 0; j < 8; ++j) {
      float4 v = *(const float4*)(s + j * 1024);
      ushort4 o; o.x = f2bf(v.x); o.y = f2bf(v.y); o.z = f2bf(v.z); o.w = f2bf(v.w);
      *(ushort4*)(d + j * 1024) = o;
    }
  } else {
    int blk = idx - 4608;
    const float* src = (blk < 256) ? w1 : w2;
    unsigned short* dst = (blk < 256) ? w1b : w2b;
    int li = ((blk & 255) * 256 + tid) * 4;  // linear n*512+k, 4 consecutive k
    int n = li >> 9, k = li & 511;
    float4 v = *(const float4*)(src + li);
    ushort4 o; o.x = f2bf(v.x); o.y = f2bf(v.y); o.z = f2bf(v.z); o.w = f2bf(v.w);
    // permuted dest: kc*16384 + (n*4 + ksg)*8 + j   (j = k&7 in {0,4} -> 8B aligned)
    int off = (k >> 5) * 16384 + ((n << 2) + ((k & 31) >> 3)) * 8 + (k & 7);
    *(ushort4*)(dst + off) = o;
  }
}

// ================= dispatch 2: gram_fac (T4 loop + permuted epilogue) ======
__global__ __launch_bounds__(256, 5) void gram_fac(
    const unsigned short* __restrict__ inpT, const float* __restrict__ partial,
    const float* __restrict__ aspect, const float* __restrict__ lenv,
    unsigned short* __restrict__ Gm, float* __restrict__ fac) {
  __shared__ unsigned short sA[2][32 * 64];
  __shared__ unsigned short sB[2][64 * 64];
  int idx = blockIdx.x;
  int tid = threadIdx.x;
  int lane = tid & 63, wave = tid >> 6;

  if (idx >= 1024) {
    float* cs = (float*)sA;
    int fblk = idx - 1024;
    int b = fblk >> 6;
    int s0 = (fblk & 63) * 16;
#pragma unroll
    for (int h = 0; h < 2; ++h) {
      int d = h * 256 + tid;
      float s = 0.f;
      const float* p = partial + (size_t)b * 32 * Dq + d;
#pragma unroll
      for (int t = 0; t < 32; ++t) s += p[t * Dq];
      cs[d] = s;
    }
    __syncthreads();
    int g = lane >> 4, lr = lane & 15;
    int row = s0 + wave * 4 + g;
    const float* a = aspect + ((size_t)b * Sq + row) * Dq + lr * 32;
    float sum = 0.f;
#pragma unroll
    for (int j = 0; j < 8; ++j) {
      float4 v = *(const float4*)(a + j * 4);
      const float* c = cs + lr * 32 + j * 4;
      sum += v.x * c[0] + v.y * c[1] + v.z * c[2] + v.w * c[3];
    }
#pragma unroll
    for (int off = 1; off < 16; off <<= 1) sum += __shfl_xor(sum, off, 64);
    if (lr == 0) {
      float len = lenv[b];
      float scale = sqrtf(len);
      float f = 0.f;
      if (row < (int)len) f = 1.f / (scale * (sum / scale + 1e-4f));
      fac[b * Sq + row] = f;
    }
    return;
  }

  const int K = 1024;
  int b = idx & 7;
  int tile = idx >> 3;
  int bm = tile & 15, bn = tile >> 4;
  const unsigned short* Ab = inpT + (size_t)b * Dq * Sq + (size_t)bm * 32 * K;
  const unsigned short* Bb = inpT + (size_t)b * Dq * Sq + (size_t)bn * 64 * K;
  int lr = lane & 15, lq = lane >> 4;
  int x7 = lr & 7;
  int l3 = lane >> 3, l7 = lane & 7;

  const unsigned short* gA = Ab + (size_t)(wave * 8 + l3) * K + (l7 ^ l3) * 8;
  const unsigned short* gB = Bb + (size_t)(wave * 16 + l3) * K + (l7 ^ l3) * 8;
  int dbaseA = (wave * 64 + lane) * 8;
  int dbaseB0 = (wave * 128 + lane) * 8;
  int dbaseB1 = (wave * 128 + 64 + lane) * 8;

  f32x4 acc[2] = {};

  auto issue = [&](int buf, int k0) {
    load_lds16(gA + k0, &sA[buf][dbaseA]);
    load_lds16(gB + k0, &sB[buf][dbaseB0]);
    load_lds16(gB + (size_t)8 * K + k0, &sB[buf][dbaseB1]);
  };

  int wm = (wave & 1) * 16, wn = (wave >> 1) * 32;
  issue(0, 0);
#pragma unroll
  for (int it = 0; it < 16; ++it) {
    int cur = it & 1;
    if (it + 1 < 16) {
      issue(cur ^ 1, (it + 1) << 6);
      asm volatile("s_waitcnt vmcnt(3)" ::: "memory");
    } else {
      asm volatile("s_waitcnt vmcnt(0)" ::: "memory");
    }
    __builtin_amdgcn_s_barrier();
#pragma unroll
    for (int c = 0; c < 2; ++c) {
      int g = c * 4 + lq;
      bf16x8 a0 = *(const bf16x8*)&sA[cur][((wm + lr) * 8 + (g ^ x7)) * 8];
      bf16x8 b0 = *(const bf16x8*)&sB[cur][((wn + lr) * 8 + (g ^ x7)) * 8];
      bf16x8 b1 = *(const bf16x8*)&sB[cur][((wn + 16 + lr) * 8 + (g ^ x7)) * 8];
      acc[0] = __builtin_amdgcn_mfma_f32_16x16x32_bf16(a0, b0, acc[0], 0, 0, 0);
      acc[1] = __builtin_amdgcn_mfma_f32_16x16x32_bf16(a0, b1, acc[1], 0, 0, 0);
    }
    asm volatile("s_waitcnt lgkmcnt(0)" ::: "memory");
    __builtin_amdgcn_sched_barrier(0);
    __builtin_amdgcn_s_barrier();
  }

  // Epilogue: write tile into the permuted layout via LDS so the global store
  // is one contiguous 4KB span. Tile rows r = bm*32 + rl (one k-chunk: kc=bm),
  // cols cc = bn*64 + ccl. Permuted offset = bm*16384 + bn*2048 + ccl*32 + rl.
  unsigned short* sP = sA[0];  // 2048 shorts needed; sA/sB reads all drained
#pragma unroll
  for (int ni = 0; ni < 2; ++ni)
#pragma unroll
    for (int i = 0; i < 4; ++i) {
      int rl = wm + lq * 4 + i;
      int ccl = wn + ni * 16 + lr;
      sP[ccl * 32 + rl] = f2bf(acc[ni][i]);
    }
  __syncthreads();
  unsigned short* Ob = Gm + (size_t)b * 512 * 512 + (size_t)bm * 16384 + (size_t)bn * 2048;
  *(bf16x8*)(Ob + tid * 8) = *(const bf16x8*)(sP + tid * 8);
}

// ================= dispatch 3: mega (contiguous stage + triple buffer) ======
#define LP 520
#define MEGA_SMEM (32 * LP * 2 + 3 * 32768 + 512)

__global__ __launch_bounds__(512, 2) void mega_ffn(
    const unsigned short* __restrict__ aspb, const unsigned short* __restrict__ G,
    const unsigned short* __restrict__ w1b, const unsigned short* __restrict__ w2b,
    const float* __restrict__ b1, const float* __restrict__ b2,
    const float* __restrict__ inp, const float* __restrict__ aspect,
    const float* __restrict__ fac, const float* __restrict__ lenv,
    float* __restrict__ out) {
  extern __shared__ char smem[];
  unsigned short* ldsA = (unsigned short*)smem;
  unsigned short* wbuf = (unsigned short*)(smem + 32 * LP * 2);
  float* ssqW = (float*)(smem + 32 * LP * 2 + 3 * 32768);
  int tid = threadIdx.x;
  int lane = tid & 63, wave = tid >> 6;
  int mg = wave >> 2, ng = wave & 3;
  int lr = lane & 15, lq = lane >> 4;
  int bid = ((blockIdx.x & 7) << 5) | (blockIdx.x >> 3);  // batch -> XCD pin
  int r0 = bid * 32;
  int b = r0 >> 10;
  int c0 = ng * 128;
  int arow = r0 + mg * 16 + lr;

  bf16x8 af[16];
  f32x4 acc[8];
  f32x4 ffnv[8];

  // B sources are pre-permuted: chunk kc is a contiguous 32KB block that is
  // byte-identical to the LDS staging image -> each load is 1KB contiguous.
  int soff = (wave * 64 + lane) * 8;  // this wave's slice within a chunk
  auto stage = [&](int buf, int kc, const unsigned short* Bsrc) {
    const unsigned short* src = Bsrc + kc * 16384;
    unsigned short* dstb = wbuf + buf * 16384;
#pragma unroll
    for (int i = 0; i < 4; ++i)
      load_lds16(src + i * 4096 + soff, dstb + i * 4096 + soff);
  };

  // Triple-buffered K-loop: stage kc+2 each step; vmcnt(8) waits only on the
  // batch issued TWO steps ago (the 8 newer loads stay in flight across the
  // barrier). Buffer (kc+2)%3 == (kc-1)%3 was released by barrier B of kc-1.
  auto gemmPhase = [&](const unsigned short* Bsrc) {
#pragma unroll
    for (int t = 0; t < 8; ++t) acc[t] = (f32x4){0.f, 0.f, 0.f, 0.f};
    stage(0, 0, Bsrc);
    stage(1, 1, Bsrc);
#pragma unroll
    for (int kc = 0; kc < 16; ++kc) {
      int cur = kc % 3;
      if (kc < 14) {
        stage((kc + 2) % 3, kc + 2, Bsrc);
        asm volatile("s_waitcnt vmcnt(8)" ::: "memory");
      } else if (kc == 14) {
        asm volatile("s_waitcnt vmcnt(4)" ::: "memory");
      } else {
        asm volatile("s_waitcnt vmcnt(0)" ::: "memory");
      }
      __builtin_amdgcn_s_barrier();  // barrier A: tile kc staged
      bf16x8 bfr[8];
#pragma unroll
      for (int t = 0; t < 8; ++t)
        bfr[t] = *(const bf16x8*)&wbuf[cur * 16384 + (size_t)((c0 + t * 16 + lr) * 4 + lq) * 8];
#pragma unroll
      for (int t = 0; t < 8; ++t)
        acc[t] = __builtin_amdgcn_mfma_f32_16x16x32_bf16(af[kc], bfr[t], acc[t], 0, 0, 0);
      asm volatile("s_waitcnt lgkmcnt(0)" ::: "memory");
      __builtin_amdgcn_sched_barrier(0);
      __builtin_amdgcn_s_barrier();  // barrier B: buf[cur] free
    }
  };

  // phase 0
#pragma unroll
  for (int j = 0; j < 16; ++j)
    af[j] = *(const bf16x8*)(aspb + (size_t)arow * 512 + j * 32 + lq * 8);
  gemmPhase(G + (size_t)b * 512 * 512);
  int len = (int)lenv[b];
  float facv[4];
#pragma unroll
  for (int i = 0; i < 4; ++i) facv[i] = fac[r0 + mg * 16 + lq * 4 + i];
#pragma unroll
  for (int t = 0; t < 8; ++t) {
#pragma unroll
    for (int i = 0; i < 4; ++i) {
      int r = r0 + mg * 16 + lq * 4 + i;
      size_t idx = (size_t)r * 512 + c0 + t * 16 + lr;
      float add = ((r & 1023) < len) ? (inp[idx] + aspect[idx]) : 0.f;
      float v = acc[t][i] * facv[i] + add;
      ffnv[t][i] = v;
      ldsA[(mg * 16 + lq * 4 + i) * LP + c0 + t * 16 + lr] = f2bf(v);
    }
  }
  __syncthreads();

  // phase 1
#pragma unroll
  for (int j = 0; j < 16; ++j)
    af[j] = *(const bf16x8*)&ldsA[(mg * 16 + lr) * LP + j * 32 + lq * 8];
  __syncthreads();
  gemmPhase(w1b);
  float biasv[8];
#pragma unroll
  for (int t = 0; t < 8; ++t) biasv[t] = b1[c0 + t * 16 + lr];
#pragma unroll
  for (int t = 0; t < 8; ++t)
#pragma unroll
    for (int i = 0; i < 4; ++i)
      ldsA[(mg * 16 + lq * 4 + i) * LP + c0 + t * 16 + lr] =
          f2bf(fmaxf(acc[t][i] + biasv[t], 0.f));
  __syncthreads();

  // phase 2 + norm
#pragma unroll
  for (int j = 0; j < 16; ++j)
    af[j] = *(const bf16x8*)&ldsA[(mg * 16 + lr) * LP + j * 32 + lq * 8];
  __syncthreads();
  gemmPhase(w2b);
#pragma unroll
  for (int t = 0; t < 8; ++t) biasv[t] = b2[c0 + t * 16 + lr];
  float ssq[4] = {0.f, 0.f, 0.f, 0.f};
#pragma unroll
  for (int t = 0; t < 8; ++t)
#pragma unroll
    for (int i = 0; i < 4; ++i) {
      float v = 2.f * ffnv[t][i] + fmaxf(acc[t][i] + biasv[t], 0.f);
      ffnv[t][i] = v;
      ssq[i] += v * v;
    }
#pragma unroll
  for (int off = 1; off < 16; off <<= 1)
#pragma unroll
    for (int i = 0; i < 4; ++i) ssq[i] += __shfl_xor(ssq[i], off, 64);
  if (lr == 0)
#pragma unroll
    for (int i = 0; i < 4; ++i) ssqW[(mg * 4 + ng) * 16 + lq * 4 + i] = ssq[i];
  __syncthreads();
  float rn[4];
#pragma unroll
  for (int i = 0; i < 4; ++i) {
    float s = ssqW[(mg * 4 + 0) * 16 + lq * 4 + i] + ssqW[(mg * 4 + 1) * 16 + lq * 4 + i] +
              ssqW[(mg * 4 + 2) * 16 + lq * 4 + i] + ssqW[(mg * 4 + 3) * 16 + lq * 4 + i];
    rn[i] = 1.f / sqrtf(s);
  }
#pragma unroll
  for (int t = 0; t < 8; ++t)
#pragma unroll
    for (int i = 0; i < 4; ++i) {
      int r = r0 + mg * 16 + lq * 4 + i;
      out[(size_t)r * 512 + c0 + t * 16 + lr] = ffnv[t][i] * rn[i];
    }
}

extern "C" void kernel_launch(void* const* d_in, const int* in_sizes, int n_in,
                              void* d_out, int out_size, void* d_ws, size_t ws_size,
                              hipStream_t stream) {
  const float* inp = (const float*)d_in[0];
  const float* inp_len = (const float*)d_in[1];
  const float* aspect = (const float*)d_in[2];
  const float* w1 = (const float*)d_in[3];
  const float* b1 = (const float*)d_in[4];
  const float* w2 = (const float*)d_in[5];
  const float* b2 = (const float*)d_in[6];
  float* out = (float*)d_out;

  char* W = (char*)d_ws;
  const size_t MB = 1ull << 20;
  unsigned short* asp_bf = (unsigned short*)(W + 0);        // 8 MB
  unsigned short* inpT   = (unsigned short*)(W + 8 * MB);   // 8 MB
  unsigned short* Gm     = (unsigned short*)(W + 16 * MB);  // 4 MB (permuted)
  unsigned short* w1bf   = (unsigned short*)(W + 20 * MB);  // 512 KB (permuted)
  unsigned short* w2bf   = (unsigned short*)(W + 20 * MB + 512 * 1024);
  float*          partial= (float*)(W + 21 * MB);           // 512 KB
  float*          fac    = (float*)(W + 22 * MB);           // 32 KB

  prep_all<<<5120, 256, 0, stream>>>(inp, aspect, w1, w2,
                                     inpT, partial, asp_bf, w1bf, w2bf);

  gram_fac<<<1536, 256, 0, stream>>>(inpT, partial, aspect, inp_len, Gm, fac);

  hipFuncSetAttribute((const void*)mega_ffn,
                      hipFuncAttributeMaxDynamicSharedMemorySize, MEGA_SMEM);
  mega_ffn<<<256, 512, MEGA_SMEM, stream>>>(
      asp_bf, Gm, w1bf, w2bf, b1, b2, inp, aspect, fac, inp_len, out);
}

// Round 4
// 143.910 us; speedup vs baseline: 1.2145x; 1.0042x over previous
//
#include <hip/hip_runtime.h>

#define Bq 8
#define Sq 1024
#define Dq 512

typedef __attribute__((ext_vector_type(8))) short bf16x8;
typedef __attribute__((ext_vector_type(4))) float f32x4;

__device__ __forceinline__ unsigned short f2bf(float f) {
  unsigned int u = __float_as_uint(f);
  return (unsigned short)((u + 0x7fffu + ((u >> 16) & 1u)) >> 16);
}

__device__ __forceinline__ void load_lds16(const unsigned short* g, unsigned short* l) {
  __builtin_amdgcn_global_load_lds(
      (const __attribute__((address_space(1))) unsigned int*)g,
      (__attribute__((address_space(3))) unsigned int*)l, 16, 0, 0);
}

// Permuted+swizzled B layout ("k-chunk-major"): element B[n][k] lives at
//   kc*16384 + n*32 + ((ksg ^ ((n>>1)&3))*8) + k7
// kc = k>>5, ksg = (k>>3)&3, k7 = k&7. Chunk = the 32KB LDS staging image.
// The XOR spreads the ds_read_b128 fragment reads over all 8 bank-quads
// (2 lanes/quad = free). Stage copy is linear; swizzle applied by producers
// (prep w-cast, gram epilogue) and by mega's ds_read address.

// ================= dispatch 1: prep_all =================
__global__ __launch_bounds__(256) void prep_all(
    const float* __restrict__ inp, const float* __restrict__ aspect,
    const float* __restrict__ w1, const float* __restrict__ w2,
    unsigned short* __restrict__ inpT, float* __restrict__ partial,
    unsigned short* __restrict__ asp_bf,
    unsigned short* __restrict__ w1b, unsigned short* __restrict__ w2b) {
  __shared__ unsigned short tile[32][33];
  __shared__ float csum[8][33];
  int idx = blockIdx.x;
  int tid = threadIdx.x;
  if (idx < 4096) {
    int b = idx & 7;
    int tt = (idx >> 3) & 31;
    int t0 = tt * 32, d0 = (idx >> 8) * 32;
    int tx = tid & 31, ty = tid >> 5;
    const float* src = inp + ((size_t)b * Sq + t0) * Dq + d0;
    float part = 0.f;
#pragma unroll
    for (int i = 0; i < 4; ++i) {
      float v = src[(size_t)(ty + i * 8) * Dq + tx];
      tile[ty + i * 8][tx] = f2bf(v);
      part += v;
    }
    csum[ty][tx] = part;
    __syncthreads();
    unsigned short* dst = inpT + (size_t)b * Dq * Sq;
#pragma unroll
    for (int i = 0; i < 4; ++i)
      dst[(size_t)(d0 + ty + i * 8) * Sq + t0 + tx] = tile[tx][ty + i * 8];
    if (ty == 0) {
      float s = 0.f;
#pragma unroll
      for (int i = 0; i < 8; ++i) s += csum[i][tx];
      partial[((size_t)b * 32 + tt) * Dq + d0 + tx] = s;
    }
  } else if (idx < 4608) {
    int blk = idx - 4096;
    const float* s = aspect + (size_t)blk * 8192 + tid * 4;
    unsigned short* d = asp_bf + (size_t)blk * 8192 + tid * 4;
#pragma unroll
    for (int j = 0; j < 8; ++j) {
      float4 v = *(const float4*)(s + j * 1024);
      ushort4 o; o.x = f2bf(v.x); o.y = f2bf(v.y); o.z = f2bf(v.z); o.w = f2bf(v.w);
      *(ushort4*)(d + j * 1024) = o;
    }
  } else {
    int blk = idx - 4608;
    const float* src = (blk < 256) ? w1 : w2;
    unsigned short* dst = (blk < 256) ? w1b : w2b;
    int li = ((blk & 255) * 256 + tid) * 4;  // linear n*512+k, 4 consecutive k
    int n = li >> 9, k = li & 511;
    float4 v = *(const float4*)(src + li);
    ushort4 o; o.x = f2bf(v.x); o.y = f2bf(v.y); o.z = f2bf(v.z); o.w = f2bf(v.w);
    int x = ((k >> 3) & 3) ^ ((n >> 1) & 3);  // bank-quad swizzle
    int off = (k >> 5) * 16384 + n * 32 + x * 8 + (k & 7);
    *(ushort4*)(dst + off) = o;
  }
}

// ================= dispatch 2: gram_fac =================
__global__ __launch_bounds__(256, 5) void gram_fac(
    const unsigned short* __restrict__ inpT, const float* __restrict__ partial,
    const float* __restrict__ aspect, const float* __restrict__ lenv,
    unsigned short* __restrict__ Gm, float* __restrict__ fac) {
  __shared__ unsigned short sA[2][32 * 64];
  __shared__ unsigned short sB[2][64 * 64];
  int idx = blockIdx.x;
  int tid = threadIdx.x;
  int lane = tid & 63, wave = tid >> 6;

  if (idx >= 1024) {
    float* cs = (float*)sA;
    int fblk = idx - 1024;
    int b = fblk >> 6;
    int s0 = (fblk & 63) * 16;
#pragma unroll
    for (int h = 0; h < 2; ++h) {
      int d = h * 256 + tid;
      float s = 0.f;
      const float* p = partial + (size_t)b * 32 * Dq + d;
#pragma unroll
      for (int t = 0; t < 32; ++t) s += p[t * Dq];
      cs[d] = s;
    }
    __syncthreads();
    int g = lane >> 4, lr = lane & 15;
    int row = s0 + wave * 4 + g;
    const float* a = aspect + ((size_t)b * Sq + row) * Dq + lr * 32;
    float sum = 0.f;
#pragma unroll
    for (int j = 0; j < 8; ++j) {
      float4 v = *(const float4*)(a + j * 4);
      const float* c = cs + lr * 32 + j * 4;
      sum += v.x * c[0] + v.y * c[1] + v.z * c[2] + v.w * c[3];
    }
#pragma unroll
    for (int off = 1; off < 16; off <<= 1) sum += __shfl_xor(sum, off, 64);
    if (lr == 0) {
      float len = lenv[b];
      float scale = sqrtf(len);
      float f = 0.f;
      if (row < (int)len) f = 1.f / (scale * (sum / scale + 1e-4f));
      fac[b * Sq + row] = f;
    }
    return;
  }

  const int K = 1024;
  int b = idx & 7;
  int tile = idx >> 3;
  int bm = tile & 15, bn = tile >> 4;
  const unsigned short* Ab = inpT + (size_t)b * Dq * Sq + (size_t)bm * 32 * K;
  const unsigned short* Bb = inpT + (size_t)b * Dq * Sq + (size_t)bn * 64 * K;
  int lr = lane & 15, lq = lane >> 4;
  int x7 = lr & 7;
  int l3 = lane >> 3, l7 = lane & 7;

  const unsigned short* gA = Ab + (size_t)(wave * 8 + l3) * K + (l7 ^ l3) * 8;
  const unsigned short* gB = Bb + (size_t)(wave * 16 + l3) * K + (l7 ^ l3) * 8;
  int dbaseA = (wave * 64 + lane) * 8;
  int dbaseB0 = (wave * 128 + lane) * 8;
  int dbaseB1 = (wave * 128 + 64 + lane) * 8;

  f32x4 acc[2] = {};

  auto issue = [&](int buf, int k0) {
    load_lds16(gA + k0, &sA[buf][dbaseA]);
    load_lds16(gB + k0, &sB[buf][dbaseB0]);
    load_lds16(gB + (size_t)8 * K + k0, &sB[buf][dbaseB1]);
  };

  int wm = (wave & 1) * 16, wn = (wave >> 1) * 32;
  issue(0, 0);
#pragma unroll
  for (int it = 0; it < 16; ++it) {
    int cur = it & 1;
    if (it + 1 < 16) {
      issue(cur ^ 1, (it + 1) << 6);
      asm volatile("s_waitcnt vmcnt(3)" ::: "memory");
    } else {
      asm volatile("s_waitcnt vmcnt(0)" ::: "memory");
    }
    __builtin_amdgcn_s_barrier();
#pragma unroll
    for (int c = 0; c < 2; ++c) {
      int g = c * 4 + lq;
      bf16x8 a0 = *(const bf16x8*)&sA[cur][((wm + lr) * 8 + (g ^ x7)) * 8];
      bf16x8 b0 = *(const bf16x8*)&sB[cur][((wn + lr) * 8 + (g ^ x7)) * 8];
      bf16x8 b1 = *(const bf16x8*)&sB[cur][((wn + 16 + lr) * 8 + (g ^ x7)) * 8];
      acc[0] = __builtin_amdgcn_mfma_f32_16x16x32_bf16(a0, b0, acc[0], 0, 0, 0);
      acc[1] = __builtin_amdgcn_mfma_f32_16x16x32_bf16(a0, b1, acc[1], 0, 0, 0);
    }
    asm volatile("s_waitcnt lgkmcnt(0)" ::: "memory");
    __builtin_amdgcn_sched_barrier(0);
    __builtin_amdgcn_s_barrier();
  }

  // Epilogue: C[r][c] stored as B[n=c][k=r] (Gram is symmetric). Chunk kc=bm,
  // within-chunk: n*32 + swz(ksg,n)*8 + k7 ; n = bn*64+ccl, k5 = rl.
  unsigned short* sP = sA[0];
#pragma unroll
  for (int ni = 0; ni < 2; ++ni)
#pragma unroll
    for (int i = 0; i < 4; ++i) {
      int rl = wm + lq * 4 + i;
      int ccl = wn + ni * 16 + lr;
      int x = (rl >> 3) ^ ((ccl >> 1) & 3);
      sP[ccl * 32 + x * 8 + (rl & 7)] = f2bf(acc[ni][i]);
    }
  __syncthreads();
  unsigned short* Ob = Gm + (size_t)b * 512 * 512 + (size_t)bm * 16384 + (size_t)bn * 2048;
  *(bf16x8*)(Ob + tid * 8) = *(const bf16x8*)(sP + tid * 8);
}

// ================= dispatch 3: mega (B-dedup waves + swizzled reads) ======
// 8 waves x (M=32 rows, N=64 cols) each: every staged B element is read by
// exactly ONE wave (32KB reads + 32KB stage-writes per k-step, conflict-free).
#define LP 520
#define MEGA_SMEM (32 * LP * 2 + 3 * 32768 + 1024)

__global__ __launch_bounds__(512, 2) void mega_ffn(
    const unsigned short* __restrict__ aspb, const unsigned short* __restrict__ G,
    const unsigned short* __restrict__ w1b, const unsigned short* __restrict__ w2b,
    const float* __restrict__ b1, const float* __restrict__ b2,
    const float* __restrict__ inp, const float* __restrict__ aspect,
    const float* __restrict__ fac, const float* __restrict__ lenv,
    float* __restrict__ out) {
  extern __shared__ char smem[];
  unsigned short* ldsA = (unsigned short*)smem;
  unsigned short* wbuf = (unsigned short*)(smem + 32 * LP * 2);
  float* ssqW = (float*)(smem + 32 * LP * 2 + 3 * 32768);
  int tid = threadIdx.x;
  int lane = tid & 63, wave = tid >> 6;
  int lr = lane & 15, lq = lane >> 4;
  int bid = ((blockIdx.x & 7) << 5) | (blockIdx.x >> 3);  // batch -> XCD pin
  int r0 = bid * 32;
  int b = r0 >> 10;
  int c0 = wave * 64;  // this wave's exclusive 64-col slice

  bf16x8 af2[2][16];   // A-frags for BOTH 16-row groups (128 VGPR)
  f32x4 acc[2][4];
  float ffnv[2][4][4];

  // swizzled ds_read base for this lane: n = c0+lr (+t*16), quad-xor from lr
  int bx = (lq ^ ((lr >> 1) & 3)) * 8;
  int rdbase = (c0 + lr) * 32 + bx;

  int soff = tid * 8;
  auto stage = [&](int buf, int kc, const unsigned short* Bsrc) {
    const unsigned short* src = Bsrc + kc * 16384;
    unsigned short* dstb = wbuf + buf * 16384;
#pragma unroll
    for (int i = 0; i < 4; ++i)
      load_lds16(src + i * 4096 + soff, dstb + i * 4096 + soff);
  };

  auto gemmPhase = [&](const unsigned short* Bsrc) {
#pragma unroll
    for (int m = 0; m < 2; ++m)
#pragma unroll
      for (int t = 0; t < 4; ++t) acc[m][t] = (f32x4){0.f, 0.f, 0.f, 0.f};
    stage(0, 0, Bsrc);
    stage(1, 1, Bsrc);
#pragma unroll
    for (int kc = 0; kc < 16; ++kc) {
      int cur = kc % 3;
      if (kc < 14) {
        stage((kc + 2) % 3, kc + 2, Bsrc);
        asm volatile("s_waitcnt vmcnt(8)" ::: "memory");
      } else if (kc == 14) {
        asm volatile("s_waitcnt vmcnt(4)" ::: "memory");
      } else {
        asm volatile("s_waitcnt vmcnt(0)" ::: "memory");
      }
      __builtin_amdgcn_s_barrier();  // barrier A: tile kc staged
      bf16x8 bfr[4];
#pragma unroll
      for (int t = 0; t < 4; ++t)
        bfr[t] = *(const bf16x8*)&wbuf[cur * 16384 + rdbase + t * 512];
#pragma unroll
      for (int t = 0; t < 4; ++t) {
        acc[0][t] = __builtin_amdgcn_mfma_f32_16x16x32_bf16(af2[0][kc], bfr[t], acc[0][t], 0, 0, 0);
        acc[1][t] = __builtin_amdgcn_mfma_f32_16x16x32_bf16(af2[1][kc], bfr[t], acc[1][t], 0, 0, 0);
      }
      asm volatile("s_waitcnt lgkmcnt(0)" ::: "memory");
      __builtin_amdgcn_sched_barrier(0);
      __builtin_amdgcn_s_barrier();  // barrier B: buf[cur] free
    }
  };

  // ================= phase 0 =================
#pragma unroll
  for (int m = 0; m < 2; ++m)
#pragma unroll
    for (int j = 0; j < 16; ++j)
      af2[m][j] = *(const bf16x8*)(aspb + (size_t)(r0 + m * 16 + lr) * 512 + j * 32 + lq * 8);
  gemmPhase(G + (size_t)b * 512 * 512);
  int len = (int)lenv[b];
  float facv[2][4];
#pragma unroll
  for (int m = 0; m < 2; ++m)
#pragma unroll
    for (int i = 0; i < 4; ++i) facv[m][i] = fac[r0 + m * 16 + lq * 4 + i];
#pragma unroll
  for (int m = 0; m < 2; ++m)
#pragma unroll
    for (int t = 0; t < 4; ++t)
#pragma unroll
      for (int i = 0; i < 4; ++i) {
        int rr = m * 16 + lq * 4 + i;
        int r = r0 + rr;
        size_t idx = (size_t)r * 512 + c0 + t * 16 + lr;
        float add = ((r & 1023) < len) ? (inp[idx] + aspect[idx]) : 0.f;
        float v = acc[m][t][i] * facv[m][i] + add;
        ffnv[m][t][i] = v;
        ldsA[rr * LP + c0 + t * 16 + lr] = f2bf(v);
      }
  __syncthreads();

  // ================= phase 1 =================
#pragma unroll
  for (int m = 0; m < 2; ++m)
#pragma unroll
    for (int j = 0; j < 16; ++j)
      af2[m][j] = *(const bf16x8*)&ldsA[(m * 16 + lr) * LP + j * 32 + lq * 8];
  __syncthreads();
  gemmPhase(w1b);
  float biasv[4];
#pragma unroll
  for (int t = 0; t < 4; ++t) biasv[t] = b1[c0 + t * 16 + lr];
#pragma unroll
  for (int m = 0; m < 2; ++m)
#pragma unroll
    for (int t = 0; t < 4; ++t)
#pragma unroll
      for (int i = 0; i < 4; ++i) {
        int rr = m * 16 + lq * 4 + i;
        ldsA[rr * LP + c0 + t * 16 + lr] = f2bf(fmaxf(acc[m][t][i] + biasv[t], 0.f));
      }
  __syncthreads();

  // ================= phase 2 + norm =================
#pragma unroll
  for (int m = 0; m < 2; ++m)
#pragma unroll
    for (int j = 0; j < 16; ++j)
      af2[m][j] = *(const bf16x8*)&ldsA[(m * 16 + lr) * LP + j * 32 + lq * 8];
  __syncthreads();
  gemmPhase(w2b);
#pragma unroll
  for (int t = 0; t < 4; ++t) biasv[t] = b2[c0 + t * 16 + lr];
  float ssq[2][4] = {{0.f, 0.f, 0.f, 0.f}, {0.f, 0.f, 0.f, 0.f}};
#pragma unroll
  for (int m = 0; m < 2; ++m)
#pragma unroll
    for (int t = 0; t < 4; ++t)
#pragma unroll
      for (int i = 0; i < 4; ++i) {
        float v = 2.f * ffnv[m][t][i] + fmaxf(acc[m][t][i] + biasv[t], 0.f);
        ffnv[m][t][i] = v;
        ssq[m][i] += v * v;
      }
#pragma unroll
  for (int off = 1; off < 16; off <<= 1)
#pragma unroll
    for (int m = 0; m < 2; ++m)
#pragma unroll
      for (int i = 0; i < 4; ++i) ssq[m][i] += __shfl_xor(ssq[m][i], off, 64);
  if (lr == 0)
#pragma unroll
    for (int m = 0; m < 2; ++m)
#pragma unroll
      for (int i = 0; i < 4; ++i) ssqW[wave * 32 + m * 16 + lq * 4 + i] = ssq[m][i];
  __syncthreads();
  float rn[2][4];
#pragma unroll
  for (int m = 0; m < 2; ++m)
#pragma unroll
    for (int i = 0; i < 4; ++i) {
      float s = 0.f;
#pragma unroll
      for (int w = 0; w < 8; ++w) s += ssqW[w * 32 + m * 16 + lq * 4 + i];
      rn[m][i] = 1.f / sqrtf(s);
    }
#pragma unroll
  for (int m = 0; m < 2; ++m)
#pragma unroll
    for (int t = 0; t < 4; ++t)
#pragma unroll
      for (int i = 0; i < 4; ++i) {
        int r = r0 + m * 16 + lq * 4 + i;
        out[(size_t)r * 512 + c0 + t * 16 + lr] = ffnv[m][t][i] * rn[m][i];
      }
}

extern "C" void kernel_launch(void* const* d_in, const int* in_sizes, int n_in,
                              void* d_out, int out_size, void* d_ws, size_t ws_size,
                              hipStream_t stream) {
  const float* inp = (const float*)d_in[0];
  const float* inp_len = (const float*)d_in[1];
  const float* aspect = (const float*)d_in[2];
  const float* w1 = (const float*)d_in[3];
  const float* b1 = (const float*)d_in[4];
  const float* w2 = (const float*)d_in[5];
  const float* b2 = (const float*)d_in[6];
  float* out = (float*)d_out;

  char* W = (char*)d_ws;
  const size_t MB = 1ull << 20;
  unsigned short* asp_bf = (unsigned short*)(W + 0);        // 8 MB
  unsigned short* inpT   = (unsigned short*)(W + 8 * MB);   // 8 MB
  unsigned short* Gm     = (unsigned short*)(W + 16 * MB);  // 4 MB (permuted+swz)
  unsigned short* w1bf   = (unsigned short*)(W + 20 * MB);  // 512 KB (permuted+swz)
  unsigned short* w2bf   = (unsigned short*)(W + 20 * MB + 512 * 1024);
  float*          partial= (float*)(W + 21 * MB);           // 512 KB
  float*          fac    = (float*)(W + 22 * MB);           // 32 KB

  prep_all<<<5120, 256, 0, stream>>>(inp, aspect, w1, w2,
                                     inpT, partial, asp_bf, w1bf, w2bf);

  gram_fac<<<1536, 256, 0, stream>>>(inpT, partial, aspect, inp_len, Gm, fac);

  hipFuncSetAttribute((const void*)mega_ffn,
                      hipFuncAttributeMaxDynamicSharedMemorySize, MEGA_SMEM);
  mega_ffn<<<256, 512, MEGA_SMEM, stream>>>(
      asp_bf, Gm, w1bf, w2bf, b1, b2, inp, aspect, fac, inp_len, out);
}